// Round 9
// baseline (446.513 us; speedup 1.0000x reference)
//
#include <hip/hip_runtime.h>

// R-GCN (3 layers) on MI355X — Round 9: flat-loop scatter with precomputed
// per-edge gather base + folded mean scale.
// L1: input-side agg + pipelined MFMA gemm (round-7 structure).
// L2/L3: dense T = h @ W^T [N,1152] (pipelined GEMM), then scat_k: per-node
// single flat 4-unrolled pass over its contiguous sorted edge range using
// sgb[e] = src*1152 + r*128 and ssc[e] = inv[dst,r] (linearity folds the
// per-relation mean into per-edge scales). Round-8 scat_k was latency-bound
// (27% VALU, 2.1 TB/s): 8 relation sub-loops of ~2 edges killed ILP.

#define DEVI __device__ __forceinline__

constexpr int NN    = 50000;
constexpr int EE    = 800000;
constexpr int RREL  = 8;
constexpr int NRSEG = NN * RREL;          // 400000
constexpr int NTC   = 1152;               // T cols = 9 groups x 128

using u16 = unsigned short;
using u32 = unsigned int;
using u64 = unsigned long long;

typedef short short8 __attribute__((ext_vector_type(8)));
typedef float f32x4  __attribute__((ext_vector_type(4)));

DEVI float bf2f(u32 u){ union{u32 i; float f;} x; x.i = u << 16; return x.f; }
DEVI u16   f2b(float f){ u32 u = __float_as_uint(f); u32 r = u + 0x7fffu + ((u >> 16) & 1u); return (u16)(r >> 16); }

typedef const __attribute__((address_space(1))) u32 gas_u32;
typedef __attribute__((address_space(3))) u32       las_u32;
DEVI void gload16(const void* g, void* l){
  __builtin_amdgcn_global_load_lds((gas_u32*)(u64)g, (las_u32*)(u64)l, 16, 0, 0);
}

// ---------------- prep kernels ----------------

__global__ void count_k(const int* __restrict__ dst, const int* __restrict__ et, int* __restrict__ cnt){
  int e = blockIdx.x * 256 + threadIdx.x;
  if(e < EE) atomicAdd(&cnt[dst[e] * RREL + et[e]], 1);
}

constexpr int SCAN_E = 8;
constexpr int CHUNK  = 2048;
constexpr int NB     = (NRSEG + CHUNK - 1) / CHUNK;   // 196

__global__ void scan1_k(const int* __restrict__ cnt, int* __restrict__ bsums){
  __shared__ int sm[256];
  int b = blockIdx.x, t = threadIdx.x;
  int base = b * CHUNK + t * SCAN_E;
  int s = 0;
  #pragma unroll
  for(int j = 0; j < SCAN_E; j++){ int i = base + j; s += (i < NRSEG) ? cnt[i] : 0; }
  sm[t] = s; __syncthreads();
  for(int off = 128; off > 0; off >>= 1){ if(t < off) sm[t] += sm[t + off]; __syncthreads(); }
  if(t == 0) bsums[b] = sm[0];
}

__global__ void scan2_k(int* __restrict__ bsums){
  __shared__ int sm[256];
  int t = threadIdx.x;
  int v = (t < NB) ? bsums[t] : 0;
  sm[t] = v; __syncthreads();
  for(int off = 1; off < 256; off <<= 1){
    int x = (t >= off) ? sm[t - off] : 0; __syncthreads();
    sm[t] += x; __syncthreads();
  }
  if(t < NB) bsums[t] = sm[t] - v;   // exclusive
}

__global__ void scan3_k(const int* __restrict__ cnt, const int* __restrict__ bsums, int* __restrict__ offs){
  __shared__ int sm[256];
  int b = blockIdx.x, t = threadIdx.x;
  int base = b * CHUNK + t * SCAN_E;
  int loc[SCAN_E]; int run = 0;
  #pragma unroll
  for(int j = 0; j < SCAN_E; j++){ int i = base + j; int c = (i < NRSEG) ? cnt[i] : 0; loc[j] = run; run += c; }
  sm[t] = run; __syncthreads();
  for(int off = 1; off < 256; off <<= 1){
    int x = (t >= off) ? sm[t - off] : 0; __syncthreads();
    sm[t] += x; __syncthreads();
  }
  int tb = bsums[b] + sm[t] - run;
  #pragma unroll
  for(int j = 0; j < SCAN_E; j++){ int i = base + j; if(i < NRSEG) offs[i] = tb + loc[j]; }
  if(b == 0 && t == 0) offs[NRSEG] = EE;
}

__global__ void inv_k(const int* __restrict__ cnt, float* __restrict__ inv){
  int i = blockIdx.x * 256 + threadIdx.x;
  if(i < NRSEG){ int c = cnt[i]; inv[i] = 1.0f / (float)(c > 0 ? c : 1); }
}

// sorted edge arrays: ssrc (src id, for agg_k), sgb (src*NTC + r*128, for
// scat_k), ssc (inv[dst,r] folded mean scale, for scat_k)
__global__ void fill_k(const int* __restrict__ src, const int* __restrict__ dst, const int* __restrict__ et,
                       const int* __restrict__ offs, const float* __restrict__ inv, int* __restrict__ fill,
                       int* __restrict__ ssrc, int* __restrict__ sgb, float* __restrict__ ssc){
  int e = blockIdx.x * 256 + threadIdx.x;
  if(e < EE){
    int d = dst[e], r = et[e];
    int seg = d * RREL + r;
    int i = atomicAdd(&fill[seg], 1);
    int p = offs[seg] + i;
    int s = src[e];
    ssrc[p] = s;
    sgb[p]  = s * NTC + r * 128;
    ssc[p]  = inv[seg];
  }
}

__global__ void castx_k(const float* __restrict__ x, u16* __restrict__ xb){
  int i = blockIdx.x * 256 + threadIdx.x;
  if(i < NN * 128) xb[i] = f2b(x[i]);
}

// Wp[g][o][i] = bf16( g<R ? W[g][i][o] : root[i][o] )   (transposed: rows contiguous in fin)
__global__ void packw_k(const float* __restrict__ w, const float* __restrict__ root,
                        u16* __restrict__ wp, int FIN, int FOUT){
  int idx = blockIdx.x * 256 + threadIdx.x;
  int tot = (RREL + 1) * FIN * FOUT;
  if(idx < tot){
    int i = idx % FIN;
    int o = (idx / FIN) % FOUT;
    int g = idx / (FIN * FOUT);
    float v = (g < RREL) ? w[((size_t)g * FIN + i) * FOUT + o] : root[(size_t)i * FOUT + o];
    wp[idx] = f2b(v);
  }
}

// ---------------- aggregation (L1, input-side): 16-lane group per segment ----------------

DEVI void acc8(float* a, uint4 v){
  a[0] += bf2f(v.x & 0xffffu); a[1] += bf2f(v.x >> 16);
  a[2] += bf2f(v.y & 0xffffu); a[3] += bf2f(v.y >> 16);
  a[4] += bf2f(v.z & 0xffffu); a[5] += bf2f(v.z >> 16);
  a[6] += bf2f(v.w & 0xffffu); a[7] += bf2f(v.w >> 16);
}

DEVI void fma8(float* a, uint4 v, float c){
  a[0] += c * bf2f(v.x & 0xffffu); a[1] += c * bf2f(v.x >> 16);
  a[2] += c * bf2f(v.y & 0xffffu); a[3] += c * bf2f(v.y >> 16);
  a[4] += c * bf2f(v.z & 0xffffu); a[5] += c * bf2f(v.z >> 16);
  a[6] += c * bf2f(v.w & 0xffffu); a[7] += c * bf2f(v.w >> 16);
}

template<int FIN, int RSUB>
__global__ __launch_bounds__(256)
void agg_k(const u16* __restrict__ hb, const int* __restrict__ ssrc,
           const int* __restrict__ offs, const float* __restrict__ inv,
           u16* __restrict__ agg, int r0)
{
  constexpr int G   = FIN / 8;               // lanes per group
  constexpr int LDW = RSUB * FIN;            // agg row stride
  const int gl  = threadIdx.x & (G - 1);
  int gid = (int)((blockIdx.x * blockDim.x + threadIdx.x) / G);
  const int ng = (int)((gridDim.x * blockDim.x) / G);
  const int S = NN * RSUB;
  for(int s = gid; s < S; s += ng){
    int n = s / RSUB, rr = s - n * RSUB;
    int seg = n * RREL + r0 + rr;
    int beg = offs[seg], end = offs[seg + 1];
    float sc = inv[seg];
    float acc[8];
    #pragma unroll
    for(int i = 0; i < 8; i++) acc[i] = 0.f;
    int e = beg;
    for(; e + 2 <= end; e += 2){
      int s0 = ssrc[e], s1 = ssrc[e + 1];
      uint4 v0 = ((const uint4*)(hb + (size_t)s0 * FIN))[gl];
      uint4 v1 = ((const uint4*)(hb + (size_t)s1 * FIN))[gl];
      acc8(acc, v0);
      acc8(acc, v1);
    }
    if(e < end){
      uint4 v0 = ((const uint4*)(hb + (size_t)ssrc[e] * FIN))[gl];
      acc8(acc, v0);
    }
    uint4 o;
    o.x = (u32)f2b(acc[0] * sc) | ((u32)f2b(acc[1] * sc) << 16);
    o.y = (u32)f2b(acc[2] * sc) | ((u32)f2b(acc[3] * sc) << 16);
    o.z = (u32)f2b(acc[4] * sc) | ((u32)f2b(acc[5] * sc) << 16);
    o.w = (u32)f2b(acc[6] * sc) | ((u32)f2b(acc[7] * sc) << 16);
    ((uint4*)(agg + (size_t)n * LDW + rr * FIN))[gl] = o;
  }
}

// ---------------- L1 GEMM: 128x256 tile, 8 waves, counted-vmcnt pipeline ----------------

template<int FIN, int NAGG, bool ROOT, int FOUT>
__global__ __launch_bounds__(512)
void gemm_k(const u16* __restrict__ Aagg, const u16* __restrict__ Aroot,
            const u16* __restrict__ Wagg, const u16* __restrict__ Wroot,
            const float* __restrict__ bias, float* __restrict__ dout,
            u16* __restrict__ hbout)
{
  static_assert(FIN % 32 == 0, "");
  constexpr int KSG = FIN / 32;
  constexpr int NG  = NAGG + (ROOT ? 1 : 0);
  constexpr int NKS = NG * KSG;
  constexpr int LDA = NAGG * FIN;
  constexpr int WN    = (FOUT == 256) ? 4 : 2;
  constexpr int WM    = 8 / WN;
  constexpr int WROWS = 128 / WM;
  constexpr int MREP  = WROWS / 16;
  constexpr int ASL = 512;
  constexpr int BSL = FOUT * 4;
  constexpr int LPS = 1 + BSL / 512;
  __shared__ u16 lds[3][(ASL + BSL) * 8];
  const int bm  = (int)blockIdx.x;
  const int tid = threadIdx.x;
  const int wid = tid >> 6, lane = tid & 63;
  const int wm  = wid / WN, wn = wid % WN;

  auto stage = [&](int ks, u16* l){
    u16* lA = l;
    u16* lB = l + ASL * 8;
    int g    = ks / KSG;
    int koff = (ks - g * KSG) * 32;
    bool isRoot = ROOT && (g == NAGG);
    {
      int sb = wid * 64;
      int s  = sb + lane;
      int pair = s >> 3, cs = s & 7;
      int c    = cs ^ (pair & 7);
      int row  = pair * 2 + (c >> 2);
      int k8   = c & 3;
      int kk   = koff + k8 * 8;
      int rowg = bm * 128 + row; rowg = rowg < NN ? rowg : NN - 1;
      const u16* ga = isRoot ? (Aroot + (size_t)rowg * FIN + kk)
                             : (Aagg + (size_t)rowg * LDA + g * FIN + kk);
      gload16(ga, lA + sb * 8);
    }
    #pragma unroll
    for(int rnd = 0; rnd < BSL / 512; rnd++){
      int sb = rnd * 512 + wid * 64;
      int s  = sb + lane;
      int pair = s >> 3, cs = s & 7;
      int c    = cs ^ (pair & 7);
      int row  = pair * 2 + (c >> 2);
      int k8   = c & 3;
      int kk   = koff + k8 * 8;
      const u16* gb = isRoot ? (Wroot + (size_t)row * FIN + kk)
                             : (Wagg + ((size_t)g * FOUT + row) * FIN + kk);
      gload16(gb, lB + sb * 8);
    }
  };

  auto ldfrag = [&](const u16* buf, int row, int k8){
    int pair = row >> 1;
    int c    = ((row & 1) << 2) + k8;
    int cs   = c ^ (pair & 7);
    return *(const short8*)(buf + pair * 64 + cs * 8);
  };

  f32x4 acc[MREP][4] = {};

  stage(0, (u16*)lds[0]);
  stage(1, (u16*)lds[1]);
  for(int ks = 0; ks < NKS; ks++){
    if(ks + 1 < NKS){
      asm volatile("s_waitcnt vmcnt(%0)" :: "i"(LPS) : "memory");
    } else {
      asm volatile("s_waitcnt vmcnt(0)" ::: "memory");
    }
    __builtin_amdgcn_sched_barrier(0);
    __builtin_amdgcn_s_barrier();
    __builtin_amdgcn_sched_barrier(0);
    if(ks + 2 < NKS) stage(ks + 2, (u16*)lds[(ks + 2) % 3]);
    const u16* lA = (const u16*)lds[ks % 3];
    const u16* lB = lA + ASL * 8;
    short8 af[MREP], bf4[4];
    #pragma unroll
    for(int m = 0; m < MREP; m++) af[m] = ldfrag(lA, wm * WROWS + m * 16 + (lane & 15), lane >> 4);
    #pragma unroll
    for(int n = 0; n < 4; n++) bf4[n] = ldfrag(lB, wn * 64 + n * 16 + (lane & 15), lane >> 4);
    #pragma unroll
    for(int m = 0; m < MREP; m++)
      #pragma unroll
      for(int n = 0; n < 4; n++)
        acc[m][n] = __builtin_amdgcn_mfma_f32_16x16x32_bf16(af[m], bf4[n], acc[m][n], 0, 0, 0);
  }

  // epilogue; C/D layout: col = lane&15, row = (lane>>4)*4 + reg   [m89-verified]
  #pragma unroll
  for(int m = 0; m < MREP; m++){
    #pragma unroll
    for(int j = 0; j < 4; j++){
      int grow = bm * 128 + wm * WROWS + m * 16 + (lane >> 4) * 4 + j;
      if(grow >= NN) continue;
      #pragma unroll
      for(int n = 0; n < 4; n++){
        int gcol = wn * 64 + n * 16 + (lane & 15);
        float v = acc[m][n][j];
        v += bias[gcol];
        v = v > 0.f ? v : expm1f(v);
        dout[(size_t)grow * 512 + gcol] = v;
        if(hbout) hbout[(size_t)grow * FOUT + gcol] = f2b(v);
      }
    }
  }
}

// ---------------- dense GEMM: T[n, jc*128+c] = sum_i A[n,i] * Bw[jc*128+c, i] ----------------

template<int FIN>
__global__ __launch_bounds__(512)
void dgemm_k(const u16* __restrict__ A, const u16* __restrict__ Bw, u16* __restrict__ T)
{
  constexpr int NKS = FIN / 32;
  constexpr int ASL = 512;
  constexpr int BSL = 512;
  constexpr int LPS = 2;
  __shared__ u16 lds[3][(ASL + BSL) * 8];
  const int bid = (int)blockIdx.x;
  const int bm  = bid / 9;
  const int jc  = bid % 9;
  const int tid = threadIdx.x;
  const int wid = tid >> 6, lane = tid & 63;
  const int wm  = wid >> 1, wn = wid & 1;      // 4x2 waves, wave tile 32x64

  auto stage = [&](int ks, u16* l){
    u16* lA = l;
    u16* lB = l + ASL * 8;
    int koff = ks * 32;
    {
      int sb = wid * 64;
      int s  = sb + lane;
      int pair = s >> 3, cs = s & 7;
      int c    = cs ^ (pair & 7);
      int row  = pair * 2 + (c >> 2);
      int k8   = c & 3;
      int kk   = koff + k8 * 8;
      int rowg = bm * 128 + row; rowg = rowg < NN ? rowg : NN - 1;
      gload16(A + (size_t)rowg * FIN + kk, lA + sb * 8);
    }
    {
      int sb = wid * 64;
      int s  = sb + lane;
      int pair = s >> 3, cs = s & 7;
      int c    = cs ^ (pair & 7);
      int row  = pair * 2 + (c >> 2);
      int k8   = c & 3;
      int kk   = koff + k8 * 8;
      gload16(Bw + ((size_t)(jc * 128 + row)) * FIN + kk, lB + sb * 8);
    }
  };

  auto ldfrag = [&](const u16* buf, int row, int k8){
    int pair = row >> 1;
    int c    = ((row & 1) << 2) + k8;
    int cs   = c ^ (pair & 7);
    return *(const short8*)(buf + pair * 64 + cs * 8);
  };

  f32x4 acc[2][4] = {};

  stage(0, (u16*)lds[0]);
  stage(1, (u16*)lds[1]);
  for(int ks = 0; ks < NKS; ks++){
    if(ks + 1 < NKS){
      asm volatile("s_waitcnt vmcnt(%0)" :: "i"(LPS) : "memory");
    } else {
      asm volatile("s_waitcnt vmcnt(0)" ::: "memory");
    }
    __builtin_amdgcn_sched_barrier(0);
    __builtin_amdgcn_s_barrier();
    __builtin_amdgcn_sched_barrier(0);
    if(ks + 2 < NKS) stage(ks + 2, (u16*)lds[(ks + 2) % 3]);
    const u16* lA = (const u16*)lds[ks % 3];
    const u16* lB = lA + ASL * 8;
    short8 af[2], bf4[4];
    #pragma unroll
    for(int m = 0; m < 2; m++) af[m] = ldfrag(lA, wm * 32 + m * 16 + (lane & 15), lane >> 4);
    #pragma unroll
    for(int n = 0; n < 4; n++) bf4[n] = ldfrag(lB, wn * 64 + n * 16 + (lane & 15), lane >> 4);
    #pragma unroll
    for(int m = 0; m < 2; m++)
      #pragma unroll
      for(int n = 0; n < 4; n++)
        acc[m][n] = __builtin_amdgcn_mfma_f32_16x16x32_bf16(af[m], bf4[n], acc[m][n], 0, 0, 0);
  }

  #pragma unroll
  for(int m = 0; m < 2; m++){
    #pragma unroll
    for(int j = 0; j < 4; j++){
      int grow = bm * 128 + wm * 32 + m * 16 + (lane >> 4) * 4 + j;
      if(grow >= NN) continue;
      #pragma unroll
      for(int n = 0; n < 4; n++){
        int gcol = wn * 64 + n * 16 + (lane & 15);
        T[(size_t)grow * NTC + jc * 128 + gcol] = f2b(acc[m][n][j]);
      }
    }
  }
}

// ---------------- scatter-mean (L2/L3, output-side): flat 4-unrolled loop ----------------
// out[n] = ELU(bias + T[n,root] + sum_e ssc[e] * T[sgb[e]+:]) over the node's
// contiguous sorted edge range.

template<bool HB>
__global__ __launch_bounds__(256)
void scat_k(const u16* __restrict__ T, const int* __restrict__ sgb,
            const float* __restrict__ ssc, const int* __restrict__ offs,
            const float* __restrict__ bias, float* __restrict__ dout, int dcol0,
            u16* __restrict__ hbout)
{
  const int gl = threadIdx.x & 15;
  int n = (int)((blockIdx.x * 256 + threadIdx.x) >> 4);
  if(n >= NN) return;
  float acc[8];
  { // root group at col 1024 (unscaled)
    uint4 v = *(const uint4*)(T + (size_t)n * NTC + 1024 + gl * 8);
    acc[0] = bf2f(v.x & 0xffffu); acc[1] = bf2f(v.x >> 16);
    acc[2] = bf2f(v.y & 0xffffu); acc[3] = bf2f(v.y >> 16);
    acc[4] = bf2f(v.z & 0xffffu); acc[5] = bf2f(v.z >> 16);
    acc[6] = bf2f(v.w & 0xffffu); acc[7] = bf2f(v.w >> 16);
  }
  int e  = offs[n * RREL];
  int e1 = offs[n * RREL + RREL];
  for(; e + 4 <= e1; e += 4){
    int   g0 = sgb[e],     g1 = sgb[e + 1], g2 = sgb[e + 2], g3 = sgb[e + 3];
    float c0 = ssc[e],     c1 = ssc[e + 1], c2 = ssc[e + 2], c3 = ssc[e + 3];
    uint4 v0 = *(const uint4*)(T + (size_t)g0 + gl * 8);
    uint4 v1 = *(const uint4*)(T + (size_t)g1 + gl * 8);
    uint4 v2 = *(const uint4*)(T + (size_t)g2 + gl * 8);
    uint4 v3 = *(const uint4*)(T + (size_t)g3 + gl * 8);
    fma8(acc, v0, c0); fma8(acc, v1, c1); fma8(acc, v2, c2); fma8(acc, v3, c3);
  }
  for(; e < e1; e++){
    uint4 v0 = *(const uint4*)(T + (size_t)sgb[e] + gl * 8);
    fma8(acc, v0, ssc[e]);
  }
  float o[8];
  #pragma unroll
  for(int i = 0; i < 8; i++){
    float v = acc[i] + bias[gl * 8 + i];
    o[i] = v > 0.f ? v : expm1f(v);
  }
  float4* dp = (float4*)(dout + (size_t)n * 512 + dcol0 + gl * 8);
  dp[0] = make_float4(o[0], o[1], o[2], o[3]);
  dp[1] = make_float4(o[4], o[5], o[6], o[7]);
  if(HB){
    uint4 hv;
    hv.x = (u32)f2b(o[0]) | ((u32)f2b(o[1]) << 16);
    hv.y = (u32)f2b(o[2]) | ((u32)f2b(o[3]) << 16);
    hv.z = (u32)f2b(o[4]) | ((u32)f2b(o[5]) << 16);
    hv.w = (u32)f2b(o[6]) | ((u32)f2b(o[7]) << 16);
    *(uint4*)(hbout + (size_t)n * 128 + gl * 8) = hv;
  }
}

// ---------------- host ----------------

extern "C" void kernel_launch(void* const* d_in, const int* in_sizes, int n_in,
                              void* d_out, int out_size, void* d_ws, size_t ws_size,
                              hipStream_t stream)
{
  const float* x     = (const float*)d_in[0];
  const int*   ei    = (const int*)d_in[1];   // [2, E] int32
  const int*   et    = (const int*)d_in[2];   // [E]
  const float* w1    = (const float*)d_in[3];
  const float* root1 = (const float*)d_in[4];
  const float* b1    = (const float*)d_in[5];
  const float* w2    = (const float*)d_in[6];
  const float* root2 = (const float*)d_in[7];
  const float* b2    = (const float*)d_in[8];
  const float* w3    = (const float*)d_in[9];
  const float* root3 = (const float*)d_in[10];
  const float* b3    = (const float*)d_in[11];
  float* out = (float*)d_out;

  const int* esrc = ei;
  const int* edst = ei + EE;

  char* w = (char*)d_ws;
  auto alloc = [&](size_t bytes)->char*{ char* p = w; w += (bytes + 255) & ~(size_t)255; return p; };
  int*   cnt   = (int*)  alloc((size_t)NRSEG * 4);
  int*   offs  = (int*)  alloc((size_t)(NRSEG + 1) * 4);
  int*   fill  = (int*)  alloc((size_t)NRSEG * 4);
  float* inv   = (float*)alloc((size_t)NRSEG * 4);
  int*   ssrc  = (int*)  alloc((size_t)EE * 4);
  int*   sgb   = (int*)  alloc((size_t)EE * 4);
  float* ssc   = (float*)alloc((size_t)EE * 4);
  u16*   xb    = (u16*)  alloc((size_t)NN * 128 * 2);
  u16*   h1b   = (u16*)  alloc((size_t)NN * 256 * 2);
  u16*   h2b   = (u16*)  alloc((size_t)NN * 128 * 2);
  u16*   wp1   = (u16*)  alloc((size_t)9 * 256 * 128 * 2);
  u16*   wp2   = (u16*)  alloc((size_t)9 * 256 * 128 * 2);
  u16*   wp3   = (u16*)  alloc((size_t)9 * 128 * 128 * 2);
  int*   bsums = (int*)  alloc(1024 * 4);
  u16*   agg   = (u16*)  alloc((size_t)NN * 1024 * 2);   // L1 input-side agg
  u16*   T     = (u16*)  alloc((size_t)NN * NTC * 2);    // L2/L3 dense transform
  (void)ws_size; (void)in_sizes; (void)n_in; (void)out_size;

  hipMemsetAsync(cnt,  0, (size_t)NRSEG * 4, stream);
  hipMemsetAsync(fill, 0, (size_t)NRSEG * 4, stream);

  count_k<<<(EE + 255) / 256, 256, 0, stream>>>(edst, et, cnt);
  scan1_k<<<NB, 256, 0, stream>>>(cnt, bsums);
  scan2_k<<<1, 256, 0, stream>>>(bsums);
  scan3_k<<<NB, 256, 0, stream>>>(cnt, bsums, offs);
  inv_k<<<(NRSEG + 255) / 256, 256, 0, stream>>>(cnt, inv);
  fill_k<<<(EE + 255) / 256, 256, 0, stream>>>(esrc, edst, et, offs, inv, fill, ssrc, sgb, ssc);
  castx_k<<<(NN * 128 + 255) / 256, 256, 0, stream>>>(x, xb);

  packw_k<<<(9 * 128 * 256 + 255) / 256, 256, 0, stream>>>(w1, root1, wp1, 128, 256);
  packw_k<<<(9 * 256 * 128 + 255) / 256, 256, 0, stream>>>(w2, root2, wp2, 256, 128);
  packw_k<<<(9 * 128 * 128 + 255) / 256, 256, 0, stream>>>(w3, root3, wp3, 128, 128);

  const int MT = (NN + 127) / 128;       // 391
  const int SB = (NN * 16 + 255) / 256;  // 3125 scatter blocks

  // Layer 1 (input-side): fin=128, fout=256
  agg_k<128, 8><<<4096, 256, 0, stream>>>(xb, ssrc, offs, inv, agg, 0);
  gemm_k<128, 8, true, 256><<<MT, 512, 0, stream>>>(
      agg, xb, wp1, wp1 + (size_t)8 * 256 * 128, b1, out + 0, h1b);

  // Layer 2 (output-side): T2 = h1 @ wp2^T [N,1152], then flat scatter-mean
  dgemm_k<256><<<MT * 9, 512, 0, stream>>>(h1b, wp2, T);
  scat_k<true><<<SB, 256, 0, stream>>>(T, sgb, ssc, offs, b2, out, 256, h2b);

  // Layer 3 (output-side): T3 = h2 @ wp3^T [N,1152], then flat scatter-mean
  dgemm_k<128><<<MT * 9, 512, 0, stream>>>(h2b, wp3, T);
  scat_k<false><<<SB, 256, 0, stream>>>(T, sgb, ssc, offs, b3, out, 384, nullptr);
}

// Round 10
// 419.217 us; speedup vs baseline: 1.0651x; 1.0651x over previous
//
#include <hip/hip_runtime.h>

// R-GCN (3 layers) on MI355X — Round 10: single packed sorted-edge array.
// Round-9 fill_k wrote 3 scattered 4B arrays per edge -> 106MB WRITE (64B
// line amplification x3). Now one array: spk[p] = (src<<3)|rel. agg_k
// unpacks src; scat_k computes the T gather base in VALU (28% busy - free)
// and reads the mean scale via broadcast inv[n*8+r].

#define DEVI __device__ __forceinline__

constexpr int NN    = 50000;
constexpr int EE    = 800000;
constexpr int RREL  = 8;
constexpr int NRSEG = NN * RREL;          // 400000
constexpr int NTC   = 1152;               // T cols = 9 groups x 128

using u16 = unsigned short;
using u32 = unsigned int;
using u64 = unsigned long long;

typedef short short8 __attribute__((ext_vector_type(8)));
typedef float f32x4  __attribute__((ext_vector_type(4)));

DEVI float bf2f(u32 u){ union{u32 i; float f;} x; x.i = u << 16; return x.f; }
DEVI u16   f2b(float f){ u32 u = __float_as_uint(f); u32 r = u + 0x7fffu + ((u >> 16) & 1u); return (u16)(r >> 16); }

typedef const __attribute__((address_space(1))) u32 gas_u32;
typedef __attribute__((address_space(3))) u32       las_u32;
DEVI void gload16(const void* g, void* l){
  __builtin_amdgcn_global_load_lds((gas_u32*)(u64)g, (las_u32*)(u64)l, 16, 0, 0);
}

// ---------------- prep kernels ----------------

__global__ void count_k(const int* __restrict__ dst, const int* __restrict__ et, int* __restrict__ cnt){
  int e = blockIdx.x * 256 + threadIdx.x;
  if(e < EE) atomicAdd(&cnt[dst[e] * RREL + et[e]], 1);
}

constexpr int SCAN_E = 8;
constexpr int CHUNK  = 2048;
constexpr int NB     = (NRSEG + CHUNK - 1) / CHUNK;   // 196

__global__ void scan1_k(const int* __restrict__ cnt, int* __restrict__ bsums){
  __shared__ int sm[256];
  int b = blockIdx.x, t = threadIdx.x;
  int base = b * CHUNK + t * SCAN_E;
  int s = 0;
  #pragma unroll
  for(int j = 0; j < SCAN_E; j++){ int i = base + j; s += (i < NRSEG) ? cnt[i] : 0; }
  sm[t] = s; __syncthreads();
  for(int off = 128; off > 0; off >>= 1){ if(t < off) sm[t] += sm[t + off]; __syncthreads(); }
  if(t == 0) bsums[b] = sm[0];
}

__global__ void scan2_k(int* __restrict__ bsums){
  __shared__ int sm[256];
  int t = threadIdx.x;
  int v = (t < NB) ? bsums[t] : 0;
  sm[t] = v; __syncthreads();
  for(int off = 1; off < 256; off <<= 1){
    int x = (t >= off) ? sm[t - off] : 0; __syncthreads();
    sm[t] += x; __syncthreads();
  }
  if(t < NB) bsums[t] = sm[t] - v;   // exclusive
}

__global__ void scan3_k(const int* __restrict__ cnt, const int* __restrict__ bsums, int* __restrict__ offs){
  __shared__ int sm[256];
  int b = blockIdx.x, t = threadIdx.x;
  int base = b * CHUNK + t * SCAN_E;
  int loc[SCAN_E]; int run = 0;
  #pragma unroll
  for(int j = 0; j < SCAN_E; j++){ int i = base + j; int c = (i < NRSEG) ? cnt[i] : 0; loc[j] = run; run += c; }
  sm[t] = run; __syncthreads();
  for(int off = 1; off < 256; off <<= 1){
    int x = (t >= off) ? sm[t - off] : 0; __syncthreads();
    sm[t] += x; __syncthreads();
  }
  int tb = bsums[b] + sm[t] - run;
  #pragma unroll
  for(int j = 0; j < SCAN_E; j++){ int i = base + j; if(i < NRSEG) offs[i] = tb + loc[j]; }
  if(b == 0 && t == 0) offs[NRSEG] = EE;
}

__global__ void inv_k(const int* __restrict__ cnt, float* __restrict__ inv){
  int i = blockIdx.x * 256 + threadIdx.x;
  if(i < NRSEG){ int c = cnt[i]; inv[i] = 1.0f / (float)(c > 0 ? c : 1); }
}

// single sorted edge array: spk[p] = (src << 3) | rel
__global__ void fill_k(const int* __restrict__ src, const int* __restrict__ dst, const int* __restrict__ et,
                       const int* __restrict__ offs, int* __restrict__ fill, int* __restrict__ spk){
  int e = blockIdx.x * 256 + threadIdx.x;
  if(e < EE){
    int d = dst[e], r = et[e];
    int seg = d * RREL + r;
    int i = atomicAdd(&fill[seg], 1);
    spk[offs[seg] + i] = (src[e] << 3) | r;
  }
}

__global__ void castx_k(const float* __restrict__ x, u16* __restrict__ xb){
  int i = blockIdx.x * 256 + threadIdx.x;
  if(i < NN * 128) xb[i] = f2b(x[i]);
}

// Wp[g][o][i] = bf16( g<R ? W[g][i][o] : root[i][o] )   (transposed: rows contiguous in fin)
__global__ void packw_k(const float* __restrict__ w, const float* __restrict__ root,
                        u16* __restrict__ wp, int FIN, int FOUT){
  int idx = blockIdx.x * 256 + threadIdx.x;
  int tot = (RREL + 1) * FIN * FOUT;
  if(idx < tot){
    int i = idx % FIN;
    int o = (idx / FIN) % FOUT;
    int g = idx / (FIN * FOUT);
    float v = (g < RREL) ? w[((size_t)g * FIN + i) * FOUT + o] : root[(size_t)i * FOUT + o];
    wp[idx] = f2b(v);
  }
}

// ---------------- aggregation (L1, input-side): 16-lane group per segment ----------------

DEVI void acc8(float* a, uint4 v){
  a[0] += bf2f(v.x & 0xffffu); a[1] += bf2f(v.x >> 16);
  a[2] += bf2f(v.y & 0xffffu); a[3] += bf2f(v.y >> 16);
  a[4] += bf2f(v.z & 0xffffu); a[5] += bf2f(v.z >> 16);
  a[6] += bf2f(v.w & 0xffffu); a[7] += bf2f(v.w >> 16);
}

DEVI void fma8(float* a, uint4 v, float c){
  a[0] += c * bf2f(v.x & 0xffffu); a[1] += c * bf2f(v.x >> 16);
  a[2] += c * bf2f(v.y & 0xffffu); a[3] += c * bf2f(v.y >> 16);
  a[4] += c * bf2f(v.z & 0xffffu); a[5] += c * bf2f(v.z >> 16);
  a[6] += c * bf2f(v.w & 0xffffu); a[7] += c * bf2f(v.w >> 16);
}

template<int FIN, int RSUB>
__global__ __launch_bounds__(256)
void agg_k(const u16* __restrict__ hb, const int* __restrict__ spk,
           const int* __restrict__ offs, const float* __restrict__ inv,
           u16* __restrict__ agg, int r0)
{
  constexpr int G   = FIN / 8;               // lanes per group
  constexpr int LDW = RSUB * FIN;            // agg row stride
  const int gl  = threadIdx.x & (G - 1);
  int gid = (int)((blockIdx.x * blockDim.x + threadIdx.x) / G);
  const int ng = (int)((gridDim.x * blockDim.x) / G);
  const int S = NN * RSUB;
  for(int s = gid; s < S; s += ng){
    int n = s / RSUB, rr = s - n * RSUB;
    int seg = n * RREL + r0 + rr;
    int beg = offs[seg], end = offs[seg + 1];
    float sc = inv[seg];
    float acc[8];
    #pragma unroll
    for(int i = 0; i < 8; i++) acc[i] = 0.f;
    int e = beg;
    for(; e + 2 <= end; e += 2){
      int s0 = spk[e] >> 3, s1 = spk[e + 1] >> 3;
      uint4 v0 = ((const uint4*)(hb + (size_t)s0 * FIN))[gl];
      uint4 v1 = ((const uint4*)(hb + (size_t)s1 * FIN))[gl];
      acc8(acc, v0);
      acc8(acc, v1);
    }
    if(e < end){
      uint4 v0 = ((const uint4*)(hb + (size_t)(spk[e] >> 3) * FIN))[gl];
      acc8(acc, v0);
    }
    uint4 o;
    o.x = (u32)f2b(acc[0] * sc) | ((u32)f2b(acc[1] * sc) << 16);
    o.y = (u32)f2b(acc[2] * sc) | ((u32)f2b(acc[3] * sc) << 16);
    o.z = (u32)f2b(acc[4] * sc) | ((u32)f2b(acc[5] * sc) << 16);
    o.w = (u32)f2b(acc[6] * sc) | ((u32)f2b(acc[7] * sc) << 16);
    ((uint4*)(agg + (size_t)n * LDW + rr * FIN))[gl] = o;
  }
}

// ---------------- L1 GEMM: 128x256 tile, 8 waves, counted-vmcnt pipeline ----------------

template<int FIN, int NAGG, bool ROOT, int FOUT>
__global__ __launch_bounds__(512)
void gemm_k(const u16* __restrict__ Aagg, const u16* __restrict__ Aroot,
            const u16* __restrict__ Wagg, const u16* __restrict__ Wroot,
            const float* __restrict__ bias, float* __restrict__ dout,
            u16* __restrict__ hbout)
{
  static_assert(FIN % 32 == 0, "");
  constexpr int KSG = FIN / 32;
  constexpr int NG  = NAGG + (ROOT ? 1 : 0);
  constexpr int NKS = NG * KSG;
  constexpr int LDA = NAGG * FIN;
  constexpr int WN    = (FOUT == 256) ? 4 : 2;
  constexpr int WM    = 8 / WN;
  constexpr int WROWS = 128 / WM;
  constexpr int MREP  = WROWS / 16;
  constexpr int ASL = 512;
  constexpr int BSL = FOUT * 4;
  constexpr int LPS = 1 + BSL / 512;
  __shared__ u16 lds[3][(ASL + BSL) * 8];
  const int bm  = (int)blockIdx.x;
  const int tid = threadIdx.x;
  const int wid = tid >> 6, lane = tid & 63;
  const int wm  = wid / WN, wn = wid % WN;

  auto stage = [&](int ks, u16* l){
    u16* lA = l;
    u16* lB = l + ASL * 8;
    int g    = ks / KSG;
    int koff = (ks - g * KSG) * 32;
    bool isRoot = ROOT && (g == NAGG);
    {
      int sb = wid * 64;
      int s  = sb + lane;
      int pair = s >> 3, cs = s & 7;
      int c    = cs ^ (pair & 7);
      int row  = pair * 2 + (c >> 2);
      int k8   = c & 3;
      int kk   = koff + k8 * 8;
      int rowg = bm * 128 + row; rowg = rowg < NN ? rowg : NN - 1;
      const u16* ga = isRoot ? (Aroot + (size_t)rowg * FIN + kk)
                             : (Aagg + (size_t)rowg * LDA + g * FIN + kk);
      gload16(ga, lA + sb * 8);
    }
    #pragma unroll
    for(int rnd = 0; rnd < BSL / 512; rnd++){
      int sb = rnd * 512 + wid * 64;
      int s  = sb + lane;
      int pair = s >> 3, cs = s & 7;
      int c    = cs ^ (pair & 7);
      int row  = pair * 2 + (c >> 2);
      int k8   = c & 3;
      int kk   = koff + k8 * 8;
      const u16* gb = isRoot ? (Wroot + (size_t)row * FIN + kk)
                             : (Wagg + ((size_t)g * FOUT + row) * FIN + kk);
      gload16(gb, lB + sb * 8);
    }
  };

  auto ldfrag = [&](const u16* buf, int row, int k8){
    int pair = row >> 1;
    int c    = ((row & 1) << 2) + k8;
    int cs   = c ^ (pair & 7);
    return *(const short8*)(buf + pair * 64 + cs * 8);
  };

  f32x4 acc[MREP][4] = {};

  stage(0, (u16*)lds[0]);
  stage(1, (u16*)lds[1]);
  for(int ks = 0; ks < NKS; ks++){
    if(ks + 1 < NKS){
      asm volatile("s_waitcnt vmcnt(%0)" :: "i"(LPS) : "memory");
    } else {
      asm volatile("s_waitcnt vmcnt(0)" ::: "memory");
    }
    __builtin_amdgcn_sched_barrier(0);
    __builtin_amdgcn_s_barrier();
    __builtin_amdgcn_sched_barrier(0);
    if(ks + 2 < NKS) stage(ks + 2, (u16*)lds[(ks + 2) % 3]);
    const u16* lA = (const u16*)lds[ks % 3];
    const u16* lB = lA + ASL * 8;
    short8 af[MREP], bf4[4];
    #pragma unroll
    for(int m = 0; m < MREP; m++) af[m] = ldfrag(lA, wm * WROWS + m * 16 + (lane & 15), lane >> 4);
    #pragma unroll
    for(int n = 0; n < 4; n++) bf4[n] = ldfrag(lB, wn * 64 + n * 16 + (lane & 15), lane >> 4);
    #pragma unroll
    for(int m = 0; m < MREP; m++)
      #pragma unroll
      for(int n = 0; n < 4; n++)
        acc[m][n] = __builtin_amdgcn_mfma_f32_16x16x32_bf16(af[m], bf4[n], acc[m][n], 0, 0, 0);
  }

  // epilogue; C/D layout: col = lane&15, row = (lane>>4)*4 + reg   [m89-verified]
  #pragma unroll
  for(int m = 0; m < MREP; m++){
    #pragma unroll
    for(int j = 0; j < 4; j++){
      int grow = bm * 128 + wm * WROWS + m * 16 + (lane >> 4) * 4 + j;
      if(grow >= NN) continue;
      #pragma unroll
      for(int n = 0; n < 4; n++){
        int gcol = wn * 64 + n * 16 + (lane & 15);
        float v = acc[m][n][j];
        v += bias[gcol];
        v = v > 0.f ? v : expm1f(v);
        dout[(size_t)grow * 512 + gcol] = v;
        if(hbout) hbout[(size_t)grow * FOUT + gcol] = f2b(v);
      }
    }
  }
}

// ---------------- dense GEMM: T[n, jc*128+c] = sum_i A[n,i] * Bw[jc*128+c, i] ----------------

template<int FIN>
__global__ __launch_bounds__(512)
void dgemm_k(const u16* __restrict__ A, const u16* __restrict__ Bw, u16* __restrict__ T)
{
  constexpr int NKS = FIN / 32;
  constexpr int ASL = 512;
  constexpr int BSL = 512;
  constexpr int LPS = 2;
  __shared__ u16 lds[3][(ASL + BSL) * 8];
  const int bid = (int)blockIdx.x;
  const int bm  = bid / 9;
  const int jc  = bid % 9;
  const int tid = threadIdx.x;
  const int wid = tid >> 6, lane = tid & 63;
  const int wm  = wid >> 1, wn = wid & 1;      // 4x2 waves, wave tile 32x64

  auto stage = [&](int ks, u16* l){
    u16* lA = l;
    u16* lB = l + ASL * 8;
    int koff = ks * 32;
    {
      int sb = wid * 64;
      int s  = sb + lane;
      int pair = s >> 3, cs = s & 7;
      int c    = cs ^ (pair & 7);
      int row  = pair * 2 + (c >> 2);
      int k8   = c & 3;
      int kk   = koff + k8 * 8;
      int rowg = bm * 128 + row; rowg = rowg < NN ? rowg : NN - 1;
      gload16(A + (size_t)rowg * FIN + kk, lA + sb * 8);
    }
    {
      int sb = wid * 64;
      int s  = sb + lane;
      int pair = s >> 3, cs = s & 7;
      int c    = cs ^ (pair & 7);
      int row  = pair * 2 + (c >> 2);
      int k8   = c & 3;
      int kk   = koff + k8 * 8;
      gload16(Bw + ((size_t)(jc * 128 + row)) * FIN + kk, lB + sb * 8);
    }
  };

  auto ldfrag = [&](const u16* buf, int row, int k8){
    int pair = row >> 1;
    int c    = ((row & 1) << 2) + k8;
    int cs   = c ^ (pair & 7);
    return *(const short8*)(buf + pair * 64 + cs * 8);
  };

  f32x4 acc[2][4] = {};

  stage(0, (u16*)lds[0]);
  stage(1, (u16*)lds[1]);
  for(int ks = 0; ks < NKS; ks++){
    if(ks + 1 < NKS){
      asm volatile("s_waitcnt vmcnt(%0)" :: "i"(LPS) : "memory");
    } else {
      asm volatile("s_waitcnt vmcnt(0)" ::: "memory");
    }
    __builtin_amdgcn_sched_barrier(0);
    __builtin_amdgcn_s_barrier();
    __builtin_amdgcn_sched_barrier(0);
    if(ks + 2 < NKS) stage(ks + 2, (u16*)lds[(ks + 2) % 3]);
    const u16* lA = (const u16*)lds[ks % 3];
    const u16* lB = lA + ASL * 8;
    short8 af[2], bf4[4];
    #pragma unroll
    for(int m = 0; m < 2; m++) af[m] = ldfrag(lA, wm * 32 + m * 16 + (lane & 15), lane >> 4);
    #pragma unroll
    for(int n = 0; n < 4; n++) bf4[n] = ldfrag(lB, wn * 64 + n * 16 + (lane & 15), lane >> 4);
    #pragma unroll
    for(int m = 0; m < 2; m++)
      #pragma unroll
      for(int n = 0; n < 4; n++)
        acc[m][n] = __builtin_amdgcn_mfma_f32_16x16x32_bf16(af[m], bf4[n], acc[m][n], 0, 0, 0);
  }

  #pragma unroll
  for(int m = 0; m < 2; m++){
    #pragma unroll
    for(int j = 0; j < 4; j++){
      int grow = bm * 128 + wm * 32 + m * 16 + (lane >> 4) * 4 + j;
      if(grow >= NN) continue;
      #pragma unroll
      for(int n = 0; n < 4; n++){
        int gcol = wn * 64 + n * 16 + (lane & 15);
        T[(size_t)grow * NTC + jc * 128 + gcol] = f2b(acc[m][n][j]);
      }
    }
  }
}

// ---------------- scatter-mean (L2/L3, output-side): flat 4-unrolled loop ----------------
// out[n] = ELU(bias + T[n,root] + sum_e inv[n*8+r_e] * T[src_e*NTC + r_e*128 +:])
// over the node's contiguous sorted edge range; src/r unpacked from spk.

template<bool HB>
__global__ __launch_bounds__(256)
void scat_k(const u16* __restrict__ T, const int* __restrict__ spk,
            const int* __restrict__ offs, const float* __restrict__ inv,
            const float* __restrict__ bias, float* __restrict__ dout, int dcol0,
            u16* __restrict__ hbout)
{
  const int gl = threadIdx.x & 15;
  int n = (int)((blockIdx.x * 256 + threadIdx.x) >> 4);
  if(n >= NN) return;
  const float* invn = inv + n * RREL;
  float acc[8];
  { // root group at col 1024 (unscaled)
    uint4 v = *(const uint4*)(T + (size_t)n * NTC + 1024 + gl * 8);
    acc[0] = bf2f(v.x & 0xffffu); acc[1] = bf2f(v.x >> 16);
    acc[2] = bf2f(v.y & 0xffffu); acc[3] = bf2f(v.y >> 16);
    acc[4] = bf2f(v.z & 0xffffu); acc[5] = bf2f(v.z >> 16);
    acc[6] = bf2f(v.w & 0xffffu); acc[7] = bf2f(v.w >> 16);
  }
  int e  = offs[n * RREL];
  int e1 = offs[n * RREL + RREL];
  for(; e + 4 <= e1; e += 4){
    int p0 = spk[e], p1 = spk[e + 1], p2 = spk[e + 2], p3 = spk[e + 3];
    uint4 v0 = *(const uint4*)(T + (size_t)(p0 >> 3) * NTC + (p0 & 7) * 128 + gl * 8);
    uint4 v1 = *(const uint4*)(T + (size_t)(p1 >> 3) * NTC + (p1 & 7) * 128 + gl * 8);
    uint4 v2 = *(const uint4*)(T + (size_t)(p2 >> 3) * NTC + (p2 & 7) * 128 + gl * 8);
    uint4 v3 = *(const uint4*)(T + (size_t)(p3 >> 3) * NTC + (p3 & 7) * 128 + gl * 8);
    fma8(acc, v0, invn[p0 & 7]); fma8(acc, v1, invn[p1 & 7]);
    fma8(acc, v2, invn[p2 & 7]); fma8(acc, v3, invn[p3 & 7]);
  }
  for(; e < e1; e++){
    int p0 = spk[e];
    uint4 v0 = *(const uint4*)(T + (size_t)(p0 >> 3) * NTC + (p0 & 7) * 128 + gl * 8);
    fma8(acc, v0, invn[p0 & 7]);
  }
  float o[8];
  #pragma unroll
  for(int i = 0; i < 8; i++){
    float v = acc[i] + bias[gl * 8 + i];
    o[i] = v > 0.f ? v : expm1f(v);
  }
  float4* dp = (float4*)(dout + (size_t)n * 512 + dcol0 + gl * 8);
  dp[0] = make_float4(o[0], o[1], o[2], o[3]);
  dp[1] = make_float4(o[4], o[5], o[6], o[7]);
  if(HB){
    uint4 hv;
    hv.x = (u32)f2b(o[0]) | ((u32)f2b(o[1]) << 16);
    hv.y = (u32)f2b(o[2]) | ((u32)f2b(o[3]) << 16);
    hv.z = (u32)f2b(o[4]) | ((u32)f2b(o[5]) << 16);
    hv.w = (u32)f2b(o[6]) | ((u32)f2b(o[7]) << 16);
    *(uint4*)(hbout + (size_t)n * 128 + gl * 8) = hv;
  }
}

// ---------------- host ----------------

extern "C" void kernel_launch(void* const* d_in, const int* in_sizes, int n_in,
                              void* d_out, int out_size, void* d_ws, size_t ws_size,
                              hipStream_t stream)
{
  const float* x     = (const float*)d_in[0];
  const int*   ei    = (const int*)d_in[1];   // [2, E] int32
  const int*   et    = (const int*)d_in[2];   // [E]
  const float* w1    = (const float*)d_in[3];
  const float* root1 = (const float*)d_in[4];
  const float* b1    = (const float*)d_in[5];
  const float* w2    = (const float*)d_in[6];
  const float* root2 = (const float*)d_in[7];
  const float* b2    = (const float*)d_in[8];
  const float* w3    = (const float*)d_in[9];
  const float* root3 = (const float*)d_in[10];
  const float* b3    = (const float*)d_in[11];
  float* out = (float*)d_out;

  const int* esrc = ei;
  const int* edst = ei + EE;

  char* w = (char*)d_ws;
  auto alloc = [&](size_t bytes)->char*{ char* p = w; w += (bytes + 255) & ~(size_t)255; return p; };
  int*   cnt   = (int*)  alloc((size_t)NRSEG * 4);
  int*   offs  = (int*)  alloc((size_t)(NRSEG + 1) * 4);
  int*   fill  = (int*)  alloc((size_t)NRSEG * 4);
  float* inv   = (float*)alloc((size_t)NRSEG * 4);
  int*   spk   = (int*)  alloc((size_t)EE * 4);
  u16*   xb    = (u16*)  alloc((size_t)NN * 128 * 2);
  u16*   h1b   = (u16*)  alloc((size_t)NN * 256 * 2);
  u16*   h2b   = (u16*)  alloc((size_t)NN * 128 * 2);
  u16*   wp1   = (u16*)  alloc((size_t)9 * 256 * 128 * 2);
  u16*   wp2   = (u16*)  alloc((size_t)9 * 256 * 128 * 2);
  u16*   wp3   = (u16*)  alloc((size_t)9 * 128 * 128 * 2);
  int*   bsums = (int*)  alloc(1024 * 4);
  u16*   agg   = (u16*)  alloc((size_t)NN * 1024 * 2);   // L1 input-side agg
  u16*   T     = (u16*)  alloc((size_t)NN * NTC * 2);    // L2/L3 dense transform
  (void)ws_size; (void)in_sizes; (void)n_in; (void)out_size;

  hipMemsetAsync(cnt,  0, (size_t)NRSEG * 4, stream);
  hipMemsetAsync(fill, 0, (size_t)NRSEG * 4, stream);

  count_k<<<(EE + 255) / 256, 256, 0, stream>>>(edst, et, cnt);
  scan1_k<<<NB, 256, 0, stream>>>(cnt, bsums);
  scan2_k<<<1, 256, 0, stream>>>(bsums);
  scan3_k<<<NB, 256, 0, stream>>>(cnt, bsums, offs);
  inv_k<<<(NRSEG + 255) / 256, 256, 0, stream>>>(cnt, inv);
  fill_k<<<(EE + 255) / 256, 256, 0, stream>>>(esrc, edst, et, offs, fill, spk);
  castx_k<<<(NN * 128 + 255) / 256, 256, 0, stream>>>(x, xb);

  packw_k<<<(9 * 128 * 256 + 255) / 256, 256, 0, stream>>>(w1, root1, wp1, 128, 256);
  packw_k<<<(9 * 256 * 128 + 255) / 256, 256, 0, stream>>>(w2, root2, wp2, 256, 128);
  packw_k<<<(9 * 128 * 128 + 255) / 256, 256, 0, stream>>>(w3, root3, wp3, 128, 128);

  const int MT = (NN + 127) / 128;       // 391
  const int SB = (NN * 16 + 255) / 256;  // 3125 scatter blocks

  // Layer 1 (input-side): fin=128, fout=256
  agg_k<128, 8><<<4096, 256, 0, stream>>>(xb, spk, offs, inv, agg, 0);
  gemm_k<128, 8, true, 256><<<MT, 512, 0, stream>>>(
      agg, xb, wp1, wp1 + (size_t)8 * 256 * 128, b1, out + 0, h1b);

  // Layer 2 (output-side): T2 = h1 @ wp2^T [N,1152], then flat scatter-mean
  dgemm_k<256><<<MT * 9, 512, 0, stream>>>(h1b, wp2, T);
  scat_k<true><<<SB, 256, 0, stream>>>(T, spk, offs, inv, b2, out, 256, h2b);

  // Layer 3 (output-side): T3 = h2 @ wp3^T [N,1152], then flat scatter-mean
  dgemm_k<128><<<MT * 9, 512, 0, stream>>>(h2b, wp3, T);
  scat_k<false><<<SB, 256, 0, stream>>>(T, spk, offs, inv, b3, out, 384, nullptr);
}